// Round 4
// baseline (269.506 us; speedup 1.0000x reference)
//
#include <hip/hip_runtime.h>
#include <hip/hip_bf16.h>
#include <cstdint>
#include <cstddef>

// ---------------------------------------------------------------------------
// bi_Mlp (fp32 I/O): out = binlin2( clip(gelu(binlin1(x))) )
// R9 -> R10:
//  * GEMM staging addresses hoisted out of the K-loop. Old code recomputed
//    (size_t)ar*K per segment per iteration with the per-lane row clamp mixed
//    in -> ~40-60 VALU ops/iter of 64-bit muls (m97 asm: 21 v_lshl_add_u64),
//    stealing SIMD issue slots from MFMA (MfmaUtil 25% + VALUBusy 40%).
//    Now: waves 0-1 stage A, waves 2-3 stage B; 8 per-lane 32-bit offsets
//    goff[t] = clamp(row)*K + ccol precomputed once; inner loop is
//    gbase + goff[t] + k0 (one v_add per load, uniform k0 folds to saddr).
//  * Everything else byte-identical to R9: 128^2 tile, K-step 64, 4 waves,
//    XOR-swizzled LDS (0 conflicts), XCD banding, grid-stride prep.
//  * Prediction: VALUBusy 40->~28, MfmaUtil 25->~31, G1 98.6->~85us.
//    Falsifier: VALU drops but dur flat -> latency-bound -> R11 = occupancy.
// ---------------------------------------------------------------------------

typedef __bf16 bf16x8 __attribute__((ext_vector_type(8)));
typedef __bf16 bf16x4 __attribute__((ext_vector_type(4)));
typedef float floatx4 __attribute__((ext_vector_type(4)));

__device__ __forceinline__ void async_load16(const void* g, void* l) {
    __builtin_amdgcn_global_load_lds(
        (const __attribute__((address_space(1))) void*)g,
        (__attribute__((address_space(3))) void*)l,
        16, 0, 0);
}

// Grid-stride prep: blocks [0, NBX) convert x fp32->bf16 (8 elem/thread/iter);
// blocks [NBX, NBX+960): one wave per weight row (w1 rows 0..3071, then w2).
__global__ __launch_bounds__(256) void prep_all(
    const float* __restrict__ x,
    const float* __restrict__ w1,
    const float* __restrict__ w2,
    __hip_bfloat16* __restrict__ xb,
    __hip_bfloat16* __restrict__ sgn1, float* __restrict__ alpha1,
    __hip_bfloat16* __restrict__ sgn2, float* __restrict__ alpha2,
    int nx8, int NBX)
{
    const int b = blockIdx.x;
    const int tid = threadIdx.x;
    if (b < NBX) {
        const float4* xv = (const float4*)x;
        bf16x8* xo = (bf16x8*)xb;
        const int stride = NBX * 256;
        for (int i = b * 256 + tid; i < nx8; i += stride) {
            float4 a = xv[2 * i];
            float4 c = xv[2 * i + 1];
            bf16x8 o;
            o[0] = (__bf16)a.x; o[1] = (__bf16)a.y;
            o[2] = (__bf16)a.z; o[3] = (__bf16)a.w;
            o[4] = (__bf16)c.x; o[5] = (__bf16)c.y;
            o[6] = (__bf16)c.z; o[7] = (__bf16)c.w;
            xo[i] = o;
        }
        return;
    }
    const int lane = tid & 63;
    const int wv = tid >> 6;
    const int wr = (b - NBX) * 4 + wv;          // 0..3839
    const float* w; __hip_bfloat16* sgn; float* alpha; int cols4; int row;
    if (wr < 3072) {
        w = w1; sgn = sgn1; alpha = alpha1; cols4 = 192; row = wr;
    } else {
        w = w2; sgn = sgn2; alpha = alpha2; cols4 = 768; row = wr - 3072;
    }
    const float4* wrp = (const float4*)w + (size_t)row * cols4;
    bf16x4* sr = (bf16x4*)sgn + (size_t)row * cols4;
    float s = 0.0f;
    for (int c = lane; c < cols4; c += 64) {
        float4 v = wrp[c];
        s += fabsf(v.x) + fabsf(v.y) + fabsf(v.z) + fabsf(v.w);
        bf16x4 o;
        o[0] = (__bf16)(v.x > 0.0f ? 1.0f : (v.x < 0.0f ? -1.0f : 0.0f));
        o[1] = (__bf16)(v.y > 0.0f ? 1.0f : (v.y < 0.0f ? -1.0f : 0.0f));
        o[2] = (__bf16)(v.z > 0.0f ? 1.0f : (v.z < 0.0f ? -1.0f : 0.0f));
        o[3] = (__bf16)(v.w > 0.0f ? 1.0f : (v.w < 0.0f ? -1.0f : 0.0f));
        sr[c] = o;
    }
    #pragma unroll
    for (int off = 32; off > 0; off >>= 1) s += __shfl_down(s, off, 64);
    if (lane == 0) alpha[row] = s / (float)(cols4 * 4);
}

__device__ __forceinline__ void store_val(__hip_bfloat16* C, size_t idx, float v) {
    C[idx] = __float2bfloat16(v);
}
__device__ __forceinline__ void store_val(float* C, size_t idx, float v) {
    C[idx] = v;
}

// C[M,N] = (A[M,K] . S[N,K]^T) * alpha[N] + bias[N]  (+ optional gelu/clip)
// 128x128 tile, K-step 64, 4 waves (2x2), 16x16x32 bf16 MFMA.
// XOR-swizzled LDS: slot s of row r holds k-chunk s^(r&7) (0 conflicts).
// 1-D grid, XCD-banded: l=(b&7)*perXcd+(b>>3); m = l/NT (band), n = l%NT.
// Staging: waves 0-1 stage A segs 0..15, waves 2-3 stage B segs 0..15;
// per-lane 32-bit offsets precomputed (k-invariant incl. row clamp).
template <bool DO_GELU, typename OutT>
__global__ __launch_bounds__(256) void gemm_bin(
    const __hip_bfloat16* __restrict__ A,
    const __hip_bfloat16* __restrict__ S,
    const float* __restrict__ alpha,
    const float* __restrict__ bias,
    OutT* __restrict__ C,
    int M, int N, int K, int T, int perXcd)
{
    constexpr int TM = 128;
    constexpr int TN = 128;
    constexpr int TK = 64;

    const int b = blockIdx.x;
    const int l = (b & 7) * perXcd + (b >> 3);
    if (l >= T) return;
    const int NT = N / TN;
    const int mt = l / NT;
    const int nt = l - mt * NT;
    const int bm = mt * TM;
    const int bn = nt * TN;

    __shared__ __align__(16) __hip_bfloat16 sA[TM * TK];
    __shared__ __align__(16) __hip_bfloat16 sB[TN * TK];

    const int tid = threadIdx.x;
    const int wave = tid >> 6;
    const int lane = tid & 63;

    const int wm = (wave & 1) * 64;
    const int wn = (wave >> 1) * 64;
    const int lr = lane & 15;         // m (A) / n (B) index within 16-tile
    const int kq = lane >> 4;         // 0..3: 8-elem k-chunk within 32-step
    const int e3 = lr & 7;            // swizzle class

    // staging: lane writes LDS offset lane*16B; fetch global chunk
    // (lane&7)^(lane>>3) so slot s of row r holds chunk s^(r&7)
    const int crow = lane >> 3;
    const int ccol = ((lane & 7) ^ crow) * 8;

    // ---- k-invariant staging addresses (hoisted; the VALU fix) ----
    // waves 0,1 -> A segs {wave*8 .. +8}; waves 2,3 -> B segs {(wave-2)*8 .. +8}
    const __hip_bfloat16* gbase;
    __hip_bfloat16* lbase;
    uint32_t goff[8];
    if (wave < 2) {
        gbase = A;
        lbase = sA + (wave * 8) * 512;
        #pragma unroll
        for (int t = 0; t < 8; t++) {
            int r = bm + (wave * 8 + t) * 8 + crow;
            r = r < M ? r : (M - 1);             // clamp tail rows (stores guarded)
            goff[t] = (uint32_t)r * (uint32_t)K + (uint32_t)ccol;
        }
    } else {
        gbase = S;
        lbase = sB + ((wave - 2) * 8) * 512;
        #pragma unroll
        for (int t = 0; t < 8; t++) {
            const int r = bn + ((wave - 2) * 8 + t) * 8 + crow;
            goff[t] = (uint32_t)r * (uint32_t)K + (uint32_t)ccol;
        }
    }

    floatx4 acc[4][4];
    #pragma unroll
    for (int i = 0; i < 4; i++)
        #pragma unroll
        for (int j = 0; j < 4; j++)
            #pragma unroll
            for (int r = 0; r < 4; r++)
                acc[i][j][r] = 0.0f;

    for (int k0 = 0; k0 < K; k0 += TK) {
        // --- stage: 8 x 16B/lane async, addresses = base + goff[t] + k0
        #pragma unroll
        for (int t = 0; t < 8; t++)
            async_load16(gbase + ((size_t)goff[t] + (uint32_t)k0),
                         (void*)(lbase + t * 512));
        __syncthreads();

        // --- compute: 2 k-steps of 32, 16 MFMAs each
        #pragma unroll
        for (int ks = 0; ks < 2; ks++) {
            const int slot = ((ks << 2) | kq) ^ e3;   // k-chunk kc = ks*4+kq
            bf16x8 af[4], bfv[4];
            #pragma unroll
            for (int i = 0; i < 4; i++)
                af[i] = *(const bf16x8*)(sA + (wm + i * 16 + lr) * TK + slot * 8);
            #pragma unroll
            for (int j = 0; j < 4; j++)
                bfv[j] = *(const bf16x8*)(sB + (wn + j * 16 + lr) * TK + slot * 8);
            #pragma unroll
            for (int i = 0; i < 4; i++)
                #pragma unroll
                for (int j = 0; j < 4; j++)
                    acc[i][j] = __builtin_amdgcn_mfma_f32_16x16x32_bf16(
                        af[i], bfv[j], acc[i][j], 0, 0, 0);
        }
        __syncthreads();
    }

    // --- epilogue: alpha/bias fp32, optional exact-erf gelu + clip
    float al[4], bi[4];
    #pragma unroll
    for (int j = 0; j < 4; j++) {
        const int col = bn + wn + j * 16 + lr;
        al[j] = alpha[col];
        bi[j] = bias[col];
    }
    #pragma unroll
    for (int i = 0; i < 4; i++) {
        const int row0 = bm + wm + i * 16 + kq * 4;
        #pragma unroll
        for (int r = 0; r < 4; r++) {
            const int row = row0 + r;
            if (row < M) {
                #pragma unroll
                for (int j = 0; j < 4; j++) {
                    float v = acc[i][j][r] * al[j] + bi[j];
                    if (DO_GELU) {
                        v = 0.5f * v * (1.0f + erff(v * 0.70710678118654752f));
                        v = fminf(fmaxf(v, -10.0f), 10.0f);
                    }
                    store_val(C, (size_t)row * N + (bn + wn + j * 16 + lr), v);
                }
            }
        }
    }
}

extern "C" void kernel_launch(void* const* d_in, const int* in_sizes, int n_in,
                              void* d_out, int out_size, void* d_ws, size_t ws_size,
                              hipStream_t stream) {
    const float* x  = (const float*)d_in[0];
    const float* w1 = (const float*)d_in[1];
    const float* b1 = (const float*)d_in[2];
    const float* w2 = (const float*)d_in[3];
    const float* b2 = (const float*)d_in[4];

    const int M = 64 * 197;   // 12608
    const int Cd = 768;
    const int Hd = 3072;

    // workspace layout (~106 MB total)
    char* ws = (char*)d_ws;
    __hip_bfloat16* xb   = (__hip_bfloat16*)ws;                 // [M, Cd]
    __hip_bfloat16* sgn1 = xb + (size_t)M * Cd;                 // [Hd, Cd]
    __hip_bfloat16* sgn2 = sgn1 + (size_t)Hd * Cd;              // [Cd, Hd]
    float* alpha1 = (float*)(sgn2 + (size_t)Cd * Hd);           // [Hd]
    float* alpha2 = alpha1 + Hd;                                // [Cd]
    __hip_bfloat16* hbuf = (__hip_bfloat16*)(alpha2 + Cd);      // [M, Hd]

    // prep: 1280 x-convert blocks (grid-stride) + 960 wave-per-row blocks
    const int nx8 = (M * Cd) / 8;          // 1,210,368 (exact)
    const int NBX = 1280;
    const int NBW = (3072 + 768) / 4;      // 960
    prep_all<<<NBX + NBW, 256, 0, stream>>>(
        x, w1, w2, xb, sgn1, alpha1, sgn2, alpha2, nx8, NBX);

    const int gm = (M + 127) / 128;        // 99

    // GEMM1: 24x99 = 2376 tiles; perXcd = 297 (exact)
    {
        const int T = (Hd / 128) * gm;
        const int perXcd = (T + 7) / 8;
        gemm_bin<true, __hip_bfloat16><<<perXcd * 8, 256, 0, stream>>>(
            xb, sgn1, alpha1, b1, hbuf, M, Hd, Cd, T, perXcd);
    }
    // GEMM2: 6x99 = 594 tiles; perXcd = 75, grid 600 (6 idle blocks)
    {
        const int T = (Cd / 128) * gm;
        const int perXcd = (T + 7) / 8;
        gemm_bin<false, float><<<perXcd * 8, 256, 0, stream>>>(
            hbuf, sgn2, alpha2, b2, (float*)d_out, M, Cd, Hd, T, perXcd);
    }
}